// Round 1
// baseline (43.413 us; speedup 1.0000x reference)
//
#include <hip/hip_runtime.h>

#define DT   0.1f
#define DT2  0.01f
#define DT3  0.001f

// ---------------------------------------------------------------------------
// Kernel 1: batch-independent Riccati table.
// The 9-state/3-control LQR decouples into 3 independent (p,v,a|jerk) axis
// problems; axes 0,1 share weights (type 0), axis 2 = yaw (type 1).
// Per t we need: Qxu (3), m = -1/Quu, K = Qxu*m (3).
// Table layout (float4): tbl[(t*2+type)*2 + 0] = {Qxu0,Qxu1,Qxu2,m}
//                        tbl[(t*2+type)*2 + 1] = {K0,K1,K2,0}
// ---------------------------------------------------------------------------
__global__ void lqr_table_kernel(float4* __restrict__ tbl) {
    int type = threadIdx.x;
    if (type >= 2) return;
    const float b0 = DT3, b1 = DT2, b2 = DT;
    const float cxp = type ? 10.f : 1.f;   // position weight (YAW_W=10)
    const float cxv = type ? 1.f : 0.f;    // velocity weight (YAW_VEL_W=1)
    const float cxa = 1.f;                 // acceleration weight
    float v00=0.f, v01=0.f, v02=0.f, v11=0.f, v12=0.f, v22=0.f; // V symmetric
    for (int t = 80; t >= 0; --t) {
        const float on = (t >= 1) ? 1.f : 0.f;   // C[0] == 0
        // Vb = V * b
        float Vb0 = v00*b0 + v01*b1 + v02*b2;
        float Vb1 = v01*b0 + v11*b1 + v12*b2;
        float Vb2 = v02*b0 + v12*b1 + v22*b2;
        float Quu = on*0.1f + b0*Vb0 + b1*Vb1 + b2*Vb2;
        // Qxu = A^T Vb,  A = [[1,DT,DT2],[0,1,DT],[0,0,1]]
        float Qxu0 = Vb0;
        float Qxu1 = fmaf(DT,  Vb0, Vb1);
        float Qxu2 = fmaf(DT2, Vb0, fmaf(DT, Vb1, Vb2));
        // M = V*A (use symmetry of V)
        float M01 = fmaf(DT, v00, v01);
        float M02 = fmaf(DT2, v00, fmaf(DT, v01, v02));
        float M11 = fmaf(DT, v01, v11);
        float M12 = fmaf(DT2, v01, fmaf(DT, v11, v12));
        float M22 = fmaf(DT2, v02, fmaf(DT, v12, v22));
        // Qxx = Cx + A^T M
        float Q00 = on*cxp + v00;
        float Q01 = M01;
        float Q02 = M02;
        float Q11 = on*cxv + fmaf(DT, M01, M11);
        float Q12 = fmaf(DT, M02, M12);
        float Q22 = on*cxa + fmaf(DT2, M02, fmaf(DT, M12, M22));
        float m = -1.f / Quu;
        tbl[(t*2+type)*2 + 0] = make_float4(Qxu0, Qxu1, Qxu2, m);
        tbl[(t*2+type)*2 + 1] = make_float4(Qxu0*m, Qxu1*m, Qxu2*m, 0.f);
        // Vn = Qxx + m * Qxu Qxu^T   (since Qux + Quu*K == 0)
        v00 = fmaf(m*Qxu0, Qxu0, Q00);
        v01 = fmaf(m*Qxu0, Qxu1, Q01);
        v02 = fmaf(m*Qxu0, Qxu2, Q02);
        v11 = fmaf(m*Qxu1, Qxu1, Q11);
        v12 = fmaf(m*Qxu1, Qxu2, Q12);
        v22 = fmaf(m*Qxu2, Qxu2, Q22);
    }
}

// ---------------------------------------------------------------------------
// Kernel 2: per-(batch, axis) backward linear pass + forward rollout.
// Block = 192 threads = 64 batches x 3 axes. Target slice (80x3 floats per
// batch, contiguous 960B) staged in LDS; per-step k overwrites the target
// slot after its last use (k_t -> slot t-1; k_0 -> slot 79, displacing the
// never-used k_80).
// LDS row stride 244 floats: 16B-aligned for float4 stores, 244%32=20 gives
// acceptable (~2.7-way) bank aliasing on the scalar step accesses.
// ---------------------------------------------------------------------------
#define BPB 64          // batches per block
#define RS  244         // LDS row stride in floats

__global__ __launch_bounds__(192, 1) void lqr_main_kernel(
        const float* __restrict__ ego,     // (8192, 9)
        const float* __restrict__ ap,      // (8192, 6, 80, 3)
        const float4* __restrict__ tbl,
        float* __restrict__ out) {         // (8192, 80, 3)
    __shared__ float sm[BPB * RS];         // 62464 B
    const int tid = threadIdx.x;
    const int b0 = blockIdx.x * BPB;

    // ---- stage targets: 64 batches x 60 float4 (coalesced) ----
    float4* s4 = (float4*)sm;
    for (int i = tid; i < BPB * 60; i += 192) {
        int bb = i / 60, c = i - bb * 60;
        const float4* src = (const float4*)(ap + (size_t)(b0 + bb) * 1440 + 1200);
        s4[bb * (RS / 4) + c] = src[c];
    }
    __syncthreads();

    const int bloc = tid / 3;
    const int axis = tid - bloc * 3;
    const int b    = b0 + bloc;
    const int type = (axis == 2) ? 1 : 0;
    const float wp = (axis == 2) ? 10.f : 1.f;
    float* row = sm + bloc * RS;

    // ---- backward pass: v-recursion, k stored into freed target slots ----
    float v0 = 0.f, v1 = 0.f, v2 = 0.f;
    for (int t = 80; t >= 1; --t) {
        float4 A4 = tbl[(t * 2 + type) * 2];        // {Qxu, m}
        int   s  = (t - 1) * 3 + axis;
        float c  = -wp * row[s];                    // c_t (position component)
        float a1 = fmaf(DT, v0, v1);                // (A^T v)[1]
        float a2 = fmaf(DT, a1, v2);                // (A^T v)[2]
        float qu = DT * a2;                         // b^T v
        float k  = qu * A4.w;                       // k_t = -qu/Quu
        v0 = (c + v0) + A4.x * k;
        v1 = a1 + A4.y * k;
        v2 = a2 + A4.z * k;
        row[s] = k;                                 // k_t -> slot t-1
    }
    {   // t = 0: c_0 = 0, only k_0 needed
        float4 A4 = tbl[type * 2];
        float a1 = fmaf(DT, v0, v1);
        float a2 = fmaf(DT, a1, v2);
        float k  = DT * a2 * A4.w;
        row[79 * 3 + axis] = k;                     // k_0 -> slot 79
    }

    // ---- forward rollout ----
    float p  = ego[b * 9 + axis];
    float ve = ego[b * 9 + 3 + axis];
    float ac = ego[b * 9 + 6 + axis];
    for (int t = 0; t < 80; ++t) {
        float4 K4 = tbl[(t * 2 + type) * 2 + 1];    // {K, _}
        int slot  = (t == 0) ? 79 : (t - 1);
        float k   = row[slot * 3 + axis];
        float u   = fmaf(K4.x, p, fmaf(K4.y, ve, fmaf(K4.z, ac, k)));
        float pn  = fmaf(DT3, u, fmaf(DT2, ac, fmaf(DT, ve, p)));
        float vn  = fmaf(DT2, u, fmaf(DT, ac, ve));
        float an  = fmaf(DT,  u, ac);
        p = pn; ve = vn; ac = an;
        out[(size_t)b * 240 + t * 3 + axis] = p;    // plan = position of x_{t+1}
    }
}

extern "C" void kernel_launch(void* const* d_in, const int* in_sizes, int n_in,
                              void* d_out, int out_size, void* d_ws, size_t ws_size,
                              hipStream_t stream) {
    const float* ego = (const float*)d_in[0];   // (8192, 9)
    const float* ap  = (const float*)d_in[1];   // (8192, 6, 80, 3)
    float*       out = (float*)d_out;           // (8192, 80, 3)
    float4*      tbl = (float4*)d_ws;           // 81*2*2 float4 = 5184 B

    lqr_table_kernel<<<1, 64, 0, stream>>>(tbl);
    lqr_main_kernel<<<8192 / BPB, 192, 0, stream>>>(ego, ap, tbl, out);
}